// Round 21
// baseline (153.737 us; speedup 1.0000x reference)
//
#include <hip/hip_runtime.h>
#include <math.h>

#define BB 32
#define TT 512
#define FF 512
#define HH 1024
#define CC 1000
#define QQ (4*HH)    // 4096 gate columns
#define FCB 8        // fc columns per block
#define KCN 8        // fc k-split chunks
#define KS  (HH/KCN) // 128 k per chunk

// ---------------- Stage 1 (fused): gate partials, 512-thread blocks ----------------
// (round-18 exact)
template<int JCH, int CHH, int JCD, int CHD>
__global__ __launch_bounds__(512, 4) void k_gates(
    const float* __restrict__ data, const float* __restrict__ h0,
    const float* __restrict__ wf, const float* __restrict__ wi,
    const float* __restrict__ wc, const float* __restrict__ wo,
    float* __restrict__ hp, float* __restrict__ dp)
{
    constexpr int LDSN = (BB*JCD > JCH) ? BB*JCD : JCH;
    __shared__ float lds[LDSN];
    const int t  = threadIdx.x;
    const int bx = blockIdx.x;
    constexpr int NH0 = 2*CHH;

    if (bx < NH0) {
        const int cb2 = bx & 1;
        const int ch  = bx >> 1;
        const int q   = cb2*2048 + t*4;
        const int gate = q >> 10;
        const int k4   = q & (HH-1);
        const float* w = (gate==0) ? wf : (gate==1) ? wi : (gate==2) ? wc : wo;
        if (t < JCH) lds[t] = h0[ch*JCH + t];
        __syncthreads();
        float4 s = make_float4(0.f,0.f,0.f,0.f);
        #pragma unroll
        for (int j = 0; j < JCH; j += 4) {
            const float4 w0 = *(const float4*)(w + (size_t)(ch*JCH + j+0)*HH + k4);
            const float4 w1 = *(const float4*)(w + (size_t)(ch*JCH + j+1)*HH + k4);
            const float4 w2 = *(const float4*)(w + (size_t)(ch*JCH + j+2)*HH + k4);
            const float4 w3 = *(const float4*)(w + (size_t)(ch*JCH + j+3)*HH + k4);
            const float h0v = lds[j+0], h1v = lds[j+1], h2v = lds[j+2], h3v = lds[j+3];
            s.x += h0v*w0.x; s.y += h0v*w0.y; s.z += h0v*w0.z; s.w += h0v*w0.w;
            s.x += h1v*w1.x; s.y += h1v*w1.y; s.z += h1v*w1.z; s.w += h1v*w1.w;
            s.x += h2v*w2.x; s.y += h2v*w2.y; s.z += h2v*w2.z; s.w += h2v*w2.w;
            s.x += h3v*w3.x; s.y += h3v*w3.y; s.z += h3v*w3.z; s.w += h3v*w3.w;
        }
        *(float4*)(hp + (size_t)ch*QQ + q) = s;
    } else {
        const int idx  = bx - NH0;
        const int cb   = idx & 15;
        const int cd   = idx >> 4;
        const int q0   = cb*256;
        const int gate = q0 >> 10;
        const int k0   = q0 & (HH-1);
        const float* w = (gate==0) ? wf : (gate==1) ? wi : (gate==2) ? wc : wo;
        const int jc0  = cd*JCD;

        for (int s = t; s < BB*JCD/4; s += 512) {
            const int b  = s / (JCD/4);
            const int jj = (s % (JCD/4))*4;
            const float4 v = *(const float4*)(data + (size_t)b*TT*FF + (size_t)(TT-1)*FF + jc0 + jj);
            lds[b*JCD + jj+0] = v.x; lds[b*JCD + jj+1] = v.y;
            lds[b*JCD + jj+2] = v.z; lds[b*JCD + jj+3] = v.w;
        }
        __syncthreads();

        const int c4 = t & 63;
        const int b0 = (t >> 6) * 4;
        const int k4 = k0 + c4*4;
        float4 acc[4];
        #pragma unroll
        for (int bi = 0; bi < 4; ++bi) acc[bi] = make_float4(0.f,0.f,0.f,0.f);

        #pragma unroll 2
        for (int j = 0; j < JCD; j += 4) {
            const float4 w0 = *(const float4*)(w + (size_t)(HH + jc0 + j+0)*HH + k4);
            const float4 w1 = *(const float4*)(w + (size_t)(HH + jc0 + j+1)*HH + k4);
            const float4 w2 = *(const float4*)(w + (size_t)(HH + jc0 + j+2)*HH + k4);
            const float4 w3 = *(const float4*)(w + (size_t)(HH + jc0 + j+3)*HH + k4);
            #pragma unroll
            for (int bi = 0; bi < 4; ++bi) {
                const float d0 = lds[(b0+bi)*JCD + j+0];
                const float d1 = lds[(b0+bi)*JCD + j+1];
                const float d2 = lds[(b0+bi)*JCD + j+2];
                const float d3 = lds[(b0+bi)*JCD + j+3];
                acc[bi].x += d0*w0.x; acc[bi].y += d0*w0.y; acc[bi].z += d0*w0.z; acc[bi].w += d0*w0.w;
                acc[bi].x += d1*w1.x; acc[bi].y += d1*w1.y; acc[bi].z += d1*w1.z; acc[bi].w += d1*w1.w;
                acc[bi].x += d2*w2.x; acc[bi].y += d2*w2.y; acc[bi].z += d2*w2.z; acc[bi].w += d2*w2.w;
                acc[bi].x += d3*w3.x; acc[bi].y += d3*w3.y; acc[bi].z += d3*w3.z; acc[bi].w += d3*w3.w;
            }
        }
        #pragma unroll
        for (int bi = 0; bi < 4; ++bi)
            *(float4*)(dp + ((size_t)cd*BB + b0 + bi)*QQ + q0 + c4*4) = acc[bi];
    }
}

// ---------------- Stage 2: reduce partials + gates -> h_last (REP diagnostic) ----------------
// grid = (HH/256 = 4, BB), block = 256. Body repeated REP times (idempotent);
// memory clobber per rep forces loads/stores to re-issue (anti-DCE).
template<int CH, int CD, int REP>
__global__ __launch_bounds__(256, 2) void k_cell(
    const float* __restrict__ hp, const float* __restrict__ dp,
    const float* __restrict__ c0, float* __restrict__ hlast)
{
    __shared__ float4 p[4][64];
    const int t    = threadIdx.x;
    const int kblk = blockIdx.x;
    const int b    = blockIdx.y;
    const int g    = t >> 6;
    const int i    = t & 63;
    const int q    = g*HH + kblk*256 + i*4;

    for (int r = 0; r < REP; ++r) {
        asm volatile("" ::: "memory");
        float4 s = make_float4(0.f,0.f,0.f,0.f);
        #pragma unroll 8
        for (int ch = 0; ch < CH; ++ch) {
            const float4 v = *(const float4*)(hp + (size_t)ch*QQ + q);
            s.x += v.x; s.y += v.y; s.z += v.z; s.w += v.w;
        }
        #pragma unroll 8
        for (int cd = 0; cd < CD; ++cd) {
            const float4 v = *(const float4*)(dp + ((size_t)cd*BB + b)*QQ + q);
            s.x += v.x; s.y += v.y; s.z += v.z; s.w += v.w;
        }
        p[g][i] = s;
        __syncthreads();

        if (t < 64) {
            const float4 gf = p[0][t], gi = p[1][t], gc = p[2][t], go = p[3][t];
            const float4 cv = *(const float4*)(c0 + kblk*256 + t*4);
            float4 h;
            { const float f=1.f/(1.f+expf(-gf.x)), ii=1.f/(1.f+expf(-gi.x)), cg=tanhf(gc.x), o=1.f/(1.f+expf(-go.x)); h.x=o*tanhf(f*cv.x+ii*cg); }
            { const float f=1.f/(1.f+expf(-gf.y)), ii=1.f/(1.f+expf(-gi.y)), cg=tanhf(gc.y), o=1.f/(1.f+expf(-go.y)); h.y=o*tanhf(f*cv.y+ii*cg); }
            { const float f=1.f/(1.f+expf(-gf.z)), ii=1.f/(1.f+expf(-gi.z)), cg=tanhf(gc.z), o=1.f/(1.f+expf(-go.z)); h.z=o*tanhf(f*cv.z+ii*cg); }
            { const float f=1.f/(1.f+expf(-gf.w)), ii=1.f/(1.f+expf(-gi.w)), cg=tanhf(gc.w), o=1.f/(1.f+expf(-go.w)); h.w=o*tanhf(f*cv.w+ii*cg); }
            *(float4*)(hlast + (size_t)b*HH + kblk*256 + t*4) = h;
        }
        __syncthreads();
    }
}

// ---------------- Stage 3a: fc partial GEMM (k-split, KCN=8) ----------------
// (round-18 exact)
__global__ __launch_bounds__(256) void k_fc_part(
    const float* __restrict__ hlast, const float* __restrict__ fcw,
    float* __restrict__ pl)
{
    __shared__ float hs[BB][KS+2];
    __shared__ float wl[FCB][KS+2];
    const int t  = threadIdx.x;
    const int c0 = blockIdx.x * FCB;
    const int kc = blockIdx.y;
    const int k0 = kc*KS;
    const int b  = t & 31;
    const int cl = t >> 5;
    const int c  = c0 + cl;

    for (int l = t; l < BB*(KS/4); l += 256) {
        const int bb = l >> 5, kk = l & 31;
        const float4 v = *(const float4*)(hlast + (size_t)bb*HH + k0 + kk*4);
        *(float2*)&hs[bb][kk*4+0] = make_float2(v.x, v.y);
        *(float2*)&hs[bb][kk*4+2] = make_float2(v.z, v.w);
    }
    for (int l = t; l < FCB*(KS/4); l += 256) {
        const int cc = l >> 5, kk = l & 31;
        const float4 v = *(const float4*)(fcw + (size_t)(c0+cc)*HH + k0 + kk*4);
        *(float2*)&wl[cc][kk*4+0] = make_float2(v.x, v.y);
        *(float2*)&wl[cc][kk*4+2] = make_float2(v.z, v.w);
    }
    __syncthreads();

    float acc = 0.f;
    #pragma unroll 16
    for (int k2 = 0; k2 < KS/2; ++k2) {
        const float2 h2 = *(const float2*)&hs[b][k2*2];
        const float2 w2 = *(const float2*)&wl[cl][k2*2];
        acc += h2.x*w2.x + h2.y*w2.y;
    }
    pl[((size_t)kc*BB + b)*CC + c] = acc;
}

// ---------------- Stage 3b: reduce + bias + relu + log_softmax (REP diagnostic) ----------------
// grid = (BB), block = 256. Idempotent body repeated REP times.
template<int REP>
__global__ __launch_bounds__(256) void k_lsm(
    const float* __restrict__ pl, const float* __restrict__ fcb,
    float* __restrict__ out)
{
    __shared__ float red[8];
    const int b = blockIdx.x, t = threadIdx.x;
    for (int r = 0; r < REP; ++r) {
        asm volatile("" ::: "memory");
        float v[4]; float vmax = -1e30f;
        #pragma unroll
        for (int ci = 0; ci < 4; ++ci) {
            const int c = t + ci*256;
            if (c < CC) {
                float s = fcb[c];
                #pragma unroll
                for (int kc = 0; kc < KCN; ++kc)
                    s += pl[((size_t)kc*BB + b)*CC + c];
                v[ci] = fmaxf(s, 0.f);
                vmax = fmaxf(vmax, v[ci]);
            } else v[ci] = -1e30f;
        }
        for (int o = 32; o > 0; o >>= 1) vmax = fmaxf(vmax, __shfl_down(vmax, o, 64));
        const int lane = t & 63, wid = t >> 6;
        if (lane == 0) red[wid] = vmax;
        __syncthreads();
        if (t == 0) red[4] = fmaxf(fmaxf(red[0], red[1]), fmaxf(red[2], red[3]));
        __syncthreads();
        const float m = red[4];
        float se = 0.f;
        #pragma unroll
        for (int ci = 0; ci < 4; ++ci) {
            const int c = t + ci*256;
            if (c < CC) se += expf(v[ci] - m);
        }
        for (int o = 32; o > 0; o >>= 1) se += __shfl_down(se, o, 64);
        if (lane == 0) red[wid] = se;
        __syncthreads();
        if (t == 0) red[5] = m + logf(red[0] + red[1] + red[2] + red[3]);
        __syncthreads();
        const float lse = red[5];
        #pragma unroll
        for (int ci = 0; ci < 4; ++ci) {
            const int c = t + ci*256;
            if (c < CC) out[(size_t)b*CC + c] = v[ci] - lse;
        }
        __syncthreads();
    }
}

extern "C" void kernel_launch(void* const* d_in, const int* in_sizes, int n_in,
                              void* d_out, int out_size, void* d_ws, size_t ws_size,
                              hipStream_t stream) {
    const float* data = (const float*)d_in[0];
    const float* h0   = (const float*)d_in[1];
    const float* c0   = (const float*)d_in[2];
    const float* wf   = (const float*)d_in[3];
    const float* wi   = (const float*)d_in[4];
    const float* wc   = (const float*)d_in[5];
    const float* wo   = (const float*)d_in[6];
    const float* fcw  = (const float*)d_in[7];
    const float* fcb  = (const float*)d_in[8];
    float* out = (float*)d_out;

    const size_t needA = ((size_t)32*QQ + (size_t)16*BB*QQ + (size_t)BB*HH + (size_t)KCN*BB*CC) * 4;
    const bool cfgA = (ws_size >= needA);

    float* ws = (float*)d_ws;
    if (cfgA) {
        float* hp = ws;                               // 32*QQ
        float* dp = hp + (size_t)32*QQ;               // 16*BB*QQ
        float* hl = dp + (size_t)16*BB*QQ;            // BB*HH
        float* pl = hl + (size_t)BB*HH;               // KCN*BB*CC
        k_gates<32,32,32,16><<<dim3(2*32 + 16*16), 512, 0, stream>>>(data, h0, wf, wi, wc, wo, hp, dp);
        k_cell<32,16,33><<<dim3(HH/256, BB), 256, 0, stream>>>(hp, dp, c0, hl);
        k_fc_part<<<dim3(CC/FCB, KCN), 256, 0, stream>>>(hl, fcw, pl);
        k_lsm<17><<<dim3(BB), 256, 0, stream>>>(pl, fcb, out);
    } else {
        float* hp = ws;                               // 32*QQ
        float* dp = hp + (size_t)32*QQ;               // 4*BB*QQ
        float* hl = dp + (size_t)4*BB*QQ;             // BB*HH
        float* pl = hl + (size_t)BB*HH;               // KCN*BB*CC
        k_gates<32,32,128,4><<<dim3(2*32 + 16*4), 512, 0, stream>>>(data, h0, wf, wi, wc, wo, hp, dp);
        k_cell<32,4,33><<<dim3(HH/256, BB), 256, 0, stream>>>(hp, dp, c0, hl);
        k_fc_part<<<dim3(CC/FCB, KCN), 256, 0, stream>>>(hl, fcw, pl);
        k_lsm<17><<<dim3(BB), 256, 0, stream>>>(pl, fcb, out);
    }
}